// Round 11
// baseline (333.201 us; speedup 1.0000x reference)
//
#include <hip/hip_runtime.h>
#include <hip/hip_cooperative_groups.h>
#include <cmath>

#pragma clang fp contract(off)

namespace cg = cooperative_groups;

#define BB 32
#define QQ 2000
#define GG 64
#define CCH 80
#define TOPC 16
#define QT 32

typedef unsigned long long u64;

// ===========================================================================
// Shared device helpers
// ===========================================================================
template <int TOPN>
__device__ __forceinline__ void block_select_raw(
    u64 (&K)[8], int tid, u64* s_tmin, u64* s_cmin, u64* s_surv,
    u64* s_sorted, u64* s_thr, int* s_ns) {
  u64 m = K[0];
  #pragma unroll
  for (int j = 1; j < 8; ++j) m = (K[j] < m) ? K[j] : m;
  s_tmin[tid] = m;
  if (tid == 0) *s_ns = 0;
  __syncthreads();

  if (tid < 64) {
    u64 c = s_tmin[tid];
    u64 c1 = s_tmin[tid + 64], c2 = s_tmin[tid + 128], c3 = s_tmin[tid + 192];
    c = (c1 < c) ? c1 : c; c = (c2 < c) ? c2 : c; c = (c3 < c) ? c3 : c;
    s_cmin[tid] = c;
    int r = 0;
    for (int j = 0; j < 64; ++j) r += (s_cmin[j] < c) ? 1 : 0;
    if (r == TOPN - 1) *s_thr = c;       // unique rank -> exactly one writer
  }
  __syncthreads();

  const u64 t = *s_thr;
  int n = 0;
  #pragma unroll
  for (int j = 0; j < 8; ++j) n += (K[j] <= t) ? 1 : 0;
  if (n) {
    int base = atomicAdd(s_ns, n);
    int k = 0;
    #pragma unroll
    for (int j = 0; j < 8; ++j) if (K[j] <= t) s_surv[base + (k++)] = K[j];
  }
  __syncthreads();

  const int ns = *s_ns;                  // TOPN <= ns <= TOPN*32
  if (ns <= 64) {
    if (tid < ns && tid < 64) {
      u64 k = s_surv[tid];
      int r = 0;
      for (int j = 0; j < ns; ++j) r += (s_surv[j] < k) ? 1 : 0;
      if (r < TOPN) s_sorted[r] = k;
    }
  } else if (tid < 64) {
    for (int pass = 0; pass < TOPN; ++pass) {
      u64 bk = ~0ull;
      for (int idx = tid; idx < ns; idx += 64) {
        u64 v = s_surv[idx]; bk = (v < bk) ? v : bk;
      }
      for (int off = 32; off; off >>= 1) {
        u64 ok = __shfl_down(bk, off, 64); bk = (ok < bk) ? ok : bk;
      }
      bk = __shfl(bk, 0, 64);
      for (int idx = tid; idx < ns; idx += 64)
        if (s_surv[idx] == bk) s_surv[idx] = ~0ull;
      if (tid == 0) s_sorted[pass] = bk;
    }
  }
  __syncthreads();
}

// ---- cost tile job (shared by mono phase1 and fallback cost_kernel) -------
__device__ __forceinline__ void cost_job(
    int b, int q0, int tid,
    const float* __restrict__ logits, const float* __restrict__ boxes,
    const int* __restrict__ gtc, const float* __restrict__ gtb,
    const float* __restrict__ szout, const float* __restrict__ sztgt,
    float* __restrict__ cost, int* __restrict__ rowarg,
    float* __restrict__ out_match,
    float4* s_qb, float4* s_qn, float* s_tile) {
#pragma clang fp contract(off)
  const int w = tid >> 6, lane = tid & 63;

  const int gbase = (b * GG + lane) * 4;
  const float g0 = gtb[gbase + 0], g1 = gtb[gbase + 1];
  const float g2 = gtb[gbase + 2], g3 = gtb[gbase + 3];
  const float t0 = g0 / sztgt[gbase + 0], t1 = g1 / sztgt[gbase + 1];
  const float t2 = g2 / sztgt[gbase + 2], t3 = g3 / sztgt[gbase + 3];
  const float garea = (g2 - g0) * (g3 - g1);
  const float gcx = (g0 + g2) * 0.5f, gcy = (g1 + g3) * 0.5f;
  const float gw = g2 - g0, gh = g3 - g1;
  const float cxlo = gcx - 2.5f * gw, cxhi = gcx + 2.5f * gw;
  const float cylo = gcy - 2.5f * gh, cyhi = gcy + 2.5f * gh;
  const int cls = gtc[b * GG + lane];

  if (tid < QT) {
    int q = q0 + tid;
    float4 bx = (q < QQ) ? reinterpret_cast<const float4*>(boxes)[b * QQ + q]
                         : make_float4(0.f, 0.f, 1.f, 1.f);
    s_qb[tid] = bx;
    float4 on;
    on.x = bx.x / szout[b * 4 + 0];
    on.y = bx.y / szout[b * 4 + 1];
    on.z = bx.z / szout[b * 4 + 2];
    on.w = bx.w / szout[b * 4 + 3];
    s_qn[tid] = on;
  }

  const float* lbase = logits + (size_t)b * QQ * CCH;
  float pv[8];
  #pragma unroll
  for (int i = 0; i < 8; ++i) {
    int q = q0 + w * 8 + i;
    pv[i] = (q < QQ) ? lbase[(size_t)q * CCH + cls] : 0.5f;
  }
  __syncthreads();

  #pragma unroll
  for (int i = 0; i < 8; ++i) {
    const int qi = w * 8 + i;
    float4 bx = s_qb[qi];
    float4 on = s_qn[qi];
    float x1 = bx.x, y1 = bx.y, x2 = bx.z, y2 = bx.w;
    float cx = (x1 + x2) * 0.5f, cy = (y1 + y2) * 0.5f;
    float areaa = (x2 - x1) * (y2 - y1);

    bool ib = (cx > g0) & (cx < g2) & (cy > g1) & (cy < g3);
    bool ic = (cx > cxlo) & (cx < cxhi) & (cy > cylo) & (cy < cyhi);
    bool fg = (__ballot(ib) != 0ull) || (__ballot(ic) != 0ull);
    float fgadd = fg ? 0.0f : 1e4f;

    float ltx = fmaxf(x1, g0), lty = fmaxf(y1, g1);
    float rbx = fminf(x2, g2), rby = fminf(y2, g3);
    float iw = fmaxf(rbx - ltx, 0.0f), ih = fmaxf(rby - lty, 0.0f);
    float inter = iw * ih;
    float uni = (areaa + garea) - inter;
    float iou = inter / uni;
    float ex1 = fminf(x1, g0), ey1 = fminf(y1, g1);
    float ex2 = fmaxf(x2, g2), ey2 = fmaxf(y2, g3);
    float ew = fmaxf(ex2 - ex1, 0.0f), eh = fmaxf(ey2 - ey1, 0.0f);
    float areac = ew * eh;
    float giou = iou - (areac - uni) / areac;

    float p = pv[i];
    float negc = (0.75f * (p * p)) * (-logf((1.0f - p) + 1e-8f));
    float posc = (0.25f * ((1.0f - p) * (1.0f - p))) * (-logf(p + 1e-8f));
    float ccls = posc - negc;

    float cb = ((fabsf(on.x - t0) + fabsf(on.y - t1)) + fabsf(on.z - t2)) + fabsf(on.w - t3);
    float notbc = (ib & ic) ? 0.0f : 1.0f;
    float c = ((5.0f * cb + 2.0f * ccls) + 2.0f * (-giou)) + 100.0f * notbc;
    c = c + fgadd;

    s_tile[qi * 65 + lane] = c;
  }
  __syncthreads();

  if (tid < QT) {
    int q = q0 + tid;
    if (q < QQ) {
      const float* row = &s_tile[tid * 65];
      float bv = row[0]; int bg = 0;
      #pragma unroll
      for (int g = 1; g < GG; ++g) {
        float cv = row[g];
        if (cv < bv) { bv = cv; bg = g; }
      }
      rowarg[b * QQ + q] = bg;
    }
  }

  float* cb_out = cost + (size_t)b * GG * QQ;
  const int qi = tid & 31;
  const int q = q0 + qi;
  if (q < QQ) {
    #pragma unroll
    for (int pass = 0; pass < 8; ++pass) {
      int g = (tid >> 5) + pass * 8;
      cb_out[(size_t)g * QQ + q] = s_tile[qi * 65 + g];
    }
  }

  int nq = QQ - q0; if (nq > QT) nq = QT;
  if (nq > 0) {
    float4* zb = reinterpret_cast<float4*>(out_match + ((size_t)b * QQ + q0) * GG);
    int n4 = nq * GG / 4;
    float4 z = make_float4(0.f, 0.f, 0.f, 0.f);
    for (int i2 = tid; i2 < n4; i2 += 256) zb[i2] = z;
  }
  __syncthreads();     // protect LDS reuse across job iterations
}

// ---- pick job (shared by mono phase2 and fallback pick_kernel) ------------
__device__ __forceinline__ void pick_job(
    int bc, int tid,
    const float* __restrict__ boxes, const float* __restrict__ gtb,
    const float* __restrict__ cost, short* __restrict__ lists,
    int* __restrict__ dynks,
    u64* s_tmin, u64* s_cmin, u64* s_surv, u64* s_sorted, u64* s_thr, int* s_ns) {
#pragma clang fp contract(off)
  const int b = bc >> 6, col = bc & 63;
  const int gbase = (b * GG + col) * 4;
  const float gx1 = gtb[gbase + 0], gy1 = gtb[gbase + 1];
  const float gx2 = gtb[gbase + 2], gy2 = gtb[gbase + 3];
  const float ga = (gx2 - gx1) * (gy2 - gy1);

  u64 K[8];
  #pragma unroll
  for (int j = 0; j < 8; ++j) {
    int q = tid * 8 + j;
    float val = -1e30f;
    if (q < QQ) {
      float4 bx = reinterpret_cast<const float4*>(boxes)[b * QQ + q];
      float areaa = (bx.z - bx.x) * (bx.w - bx.y);
      float ltx = fmaxf(bx.x, gx1), lty = fmaxf(bx.y, gy1);
      float rbx = fminf(bx.z, gx2), rby = fminf(bx.w, gy2);
      float iw = fmaxf(rbx - ltx, 0.0f), ih = fmaxf(rby - lty, 0.0f);
      float inter = iw * ih;
      val = inter / ((areaa + ga) - inter);
    }
    unsigned u = __float_as_uint(val);
    u = (u & 0x80000000u) ? ~u : (u | 0x80000000u);
    K[j] = ~(((u64)u << 16) | (u64)(0xFFFF - q));
  }
  block_select_raw<5>(K, tid, s_tmin, s_cmin, s_surv, s_sorted, s_thr, s_ns);
  if (tid == 0) {
    float s = 0.0f;
    for (int r = 0; r < 5; ++r) {        // descending iou, left-assoc sum
      u64 kk = ~s_sorted[r];
      unsigned u = (unsigned)(kk >> 16);
      u = (u & 0x80000000u) ? (u & 0x7FFFFFFFu) : ~u;
      s += __uint_as_float(u);
    }
    int dynk = (int)s;                   // trunc == astype(int32)
    if (dynk < 1) dynk = 1;
    dynks[bc] = dynk;
  }

  const float* ccol = cost + (size_t)bc * QQ;
  {
    float cv[8];
    if (tid < 249) {
      const float4* c4 = reinterpret_cast<const float4*>(ccol) + tid * 2;
      float4 a = c4[0], d = c4[1];
      cv[0] = a.x; cv[1] = a.y; cv[2] = a.z; cv[3] = a.w;
      cv[4] = d.x; cv[5] = d.y; cv[6] = d.z; cv[7] = d.w;
    } else {
      #pragma unroll
      for (int j = 0; j < 8; ++j) {
        int q = tid * 8 + j;
        cv[j] = (q < QQ) ? ccol[q] : INFINITY;
      }
    }
    #pragma unroll
    for (int j = 0; j < 8; ++j) {
      unsigned u = __float_as_uint(cv[j]);
      u = (u & 0x80000000u) ? ~u : (u | 0x80000000u);
      K[j] = ((u64)u << 16) | (u64)(tid * 8 + j);
    }
  }
  block_select_raw<TOPC>(K, tid, s_tmin, s_cmin, s_surv, s_sorted, s_thr, s_ns);
  if (tid < TOPC) lists[bc * TOPC + tid] = (short)(s_sorted[tid] & 0xFFFFull);
  __syncthreads();
}

// ---- serial job (shared by mono phase3 and fallback serial_kernel) --------
// LDS passed explicitly; s_first is SHORT here (values in [-1, 65]).
struct SerialLds {
  unsigned mlo[QQ], mhi[QQ];
  short first[QQ];
  unsigned char mq[QQ];
  short rarg[QQ];
  int cnt[GG];
  u64 pack[GG];
  int added[GG];
  int nadd, Tv;
};

__device__ __forceinline__ void serial_job(
    int b, int tid, SerialLds* sp,
    const float* __restrict__ cost, const short* __restrict__ lists,
    const int* __restrict__ dynks, const int* __restrict__ rowarg,
    float* __restrict__ out_match, float* __restrict__ out_ids) {
#pragma clang fp contract(off)
  for (int q = tid; q < QQ; q += 256) {
    sp->mlo[q] = 0u; sp->mhi[q] = 0u; sp->first[q] = -1; sp->mq[q] = 0;
    sp->rarg[q] = (short)rowarg[b * QQ + q];
  }
  if (tid < GG) sp->cnt[tid] = 0;
  __syncthreads();

  if (tid < GG) {
    int dynk = dynks[b * GG + tid];
    sp->cnt[tid] = dynk;
    const short* lrow = lists + (b * GG + tid) * TOPC;
    for (int i = 0; i < dynk; ++i) {
      int q = lrow[i];
      if (tid < 32) atomicOr(&sp->mlo[q], 1u << tid);
      else          atomicOr(&sp->mhi[q], 1u << (tid - 32));
      sp->first[q] = 0;                  // benign same-value race
      sp->mq[q] = 1;
    }
  }
  __syncthreads();

  for (int q = tid; q < QQ; q += 256) {
    unsigned lo = sp->mlo[q], hi = sp->mhi[q];
    if (__popc(lo) + __popc(hi) > 1) {
      int bg = sp->rarg[q];
      unsigned tl = lo, th = hi;
      while (tl) { int g = __ffs(tl) - 1; tl &= tl - 1; if (g != bg) atomicSub(&sp->cnt[g], 1); }
      while (th) { int g = __ffs(th) + 31; th &= th - 1; if (g != bg) atomicSub(&sp->cnt[g], 1); }
      bool had = (bg < 32) ? ((lo >> bg) & 1u) : ((hi >> (bg - 32)) & 1u);
      if (!had) atomicAdd(&sp->cnt[bg], 1);
      sp->mlo[q] = (bg < 32) ? (1u << bg) : 0u;
      sp->mhi[q] = (bg >= 32) ? (1u << (bg - 32)) : 0u;
    }
  }
  __syncthreads();

  const float* costb = cost + (size_t)b * GG * QQ;

  if (tid < 64) {
    const int lane = tid;
    unsigned cand[8];
    {
      const unsigned* lrow =
          reinterpret_cast<const unsigned*>(lists + (b * GG + lane) * TOPC);
      #pragma unroll
      for (int j = 0; j < 8; ++j) cand[j] = lrow[j];
    }
    int T = 0;
    for (int iter = 0; iter < GG; ++iter) {
      unsigned long long bal = __ballot(sp->cnt[lane] > 0);
      unsigned long long um = ~bal;
      if (um == 0ull) break;
      T++;
      bool isun = (um >> lane) & 1ull;
      if (lane == 0) sp->nadd = 0;

      int myq = -1;
      unsigned fmask = 0;
      if (isun) {
        #pragma unroll
        for (int i = 0; i < 16; ++i) {
          int cq = (cand[i >> 1] >> (16 * (i & 1))) & 0xFFFF;
          fmask |= ((unsigned)(sp->mq[cq] == 0)) << i;
        }
        if (fmask) {
          int idx = __ffs(fmask) - 1;
          myq = (cand[idx >> 1] >> (16 * (idx & 1))) & 0xFFFF;
        }
      }

      unsigned long long fb = __ballot(isun && fmask == 0);
      while (fb) {
        int col = __ffsll(fb) - 1; fb &= fb - 1;
        const float* ccol = costb + (size_t)col * QQ;
        float bv = INFINITY; int bq = 0x7fffffff;
        for (int q2 = lane; q2 < QQ; q2 += 64) {
          if (sp->mq[q2] == 0) {
            float cv = ccol[q2];
            if (cv < bv) { bv = cv; bq = q2; }
          }
        }
        for (int off = 32; off; off >>= 1) {
          float ov = __shfl_down(bv, off, 64); int oq = __shfl_down(bq, off, 64);
          if (ov < bv || (ov == bv && oq < bq)) { bv = ov; bq = oq; }
        }
        bq = __shfl(bq, 0, 64);
        if (bq == 0x7fffffff) {
          bv = INFINITY; bq = 0x7fffffff;
          for (int q2 = lane; q2 < QQ; q2 += 64) {
            float cv = ccol[q2];
            int k = (sp->first[q2] >= 0) ? (iter + 1 - sp->first[q2]) : 0;
            for (int tt = 0; tt < k; ++tt) cv += 1e5f;
            if (cv < bv) { bv = cv; bq = q2; }
          }
          for (int off = 32; off; off >>= 1) {
            float ov = __shfl_down(bv, off, 64); int oq = __shfl_down(bq, off, 64);
            if (ov < bv || (ov == bv && oq < bq)) { bv = ov; bq = oq; }
          }
          bq = __shfl(bq, 0, 64);
        }
        if (lane == col) myq = bq;
      }

      if (isun) {
        int q = myq;
        if (lane < 32) atomicOr(&sp->mlo[q], 1u << lane);
        else           atomicOr(&sp->mhi[q], 1u << (lane - 32));
        atomicAdd(&sp->cnt[lane], 1);
        if (sp->first[q] < 0) sp->first[q] = (short)(iter + 1);
        sp->mq[q] = 1;
        int slot = atomicAdd(&sp->nadd, 1);
        sp->added[slot] = q;
      }

      int na = sp->nadd;
      if (lane < na) {
        int q = sp->added[lane];
        bool dup = false;
        for (int j = 0; j < lane; ++j) dup = dup || (sp->added[j] == q);
        if (!dup) {
          unsigned lo = sp->mlo[q], hi = sp->mhi[q];
          if (__popc(lo) + __popc(hi) > 1) {
            int bg = sp->rarg[q];
            unsigned tl = lo, th = hi;
            while (tl) { int g = __ffs(tl) - 1; tl &= tl - 1; if (g != bg) atomicSub(&sp->cnt[g], 1); }
            while (th) { int g = __ffs(th) + 31; th &= th - 1; if (g != bg) atomicSub(&sp->cnt[g], 1); }
            bool had = (bg < 32) ? ((lo >> bg) & 1u) : ((hi >> (bg - 32)) & 1u);
            if (!had) atomicAdd(&sp->cnt[bg], 1);
            sp->mlo[q] = (bg < 32) ? (1u << bg) : 0u;
            sp->mhi[q] = (bg >= 32) ? (1u << (bg - 32)) : 0u;
          }
        }
      }
    }
    if (tid == 0) sp->Tv = T;
  }
  __syncthreads();
  const int T = sp->Tv;

  if (tid < GG) sp->pack[tid] = 0xFFFFFFFFFFFFFFFFull;
  __syncthreads();
  for (int q = tid; q < QQ; q += 256) {
    unsigned lo = sp->mlo[q], hi = sp->mhi[q];
    if (lo | hi) {
      int g = lo ? (__ffs(lo) - 1) : (__ffs(hi) + 31);
      float cv = costb[(size_t)g * QQ + q];
      int k = T - sp->first[q];
      for (int tt = 0; tt < k; ++tt) cv += 1e5f;
      unsigned ub = __float_as_uint(cv);
      ub = (ub & 0x80000000u) ? ~ub : (ub | 0x80000000u);
      u64 pk = ((u64)ub << 16) | (unsigned)q;
      atomicMin(&sp->pack[g], pk);
    }
  }
  __syncthreads();
  if (tid < GG) {
    u64 pk = sp->pack[tid];
    out_ids[b * GG + tid] =
        (pk == 0xFFFFFFFFFFFFFFFFull) ? 0.0f : (float)(pk & 0xFFFFull);
  }
  for (int q = tid; q < QQ; q += 256) {
    unsigned lo = sp->mlo[q], hi = sp->mhi[q];
    if (lo | hi) {
      int g = lo ? (__ffs(lo) - 1) : (__ffs(hi) + 31);
      out_match[((size_t)b * QQ + q) * GG + g] = 1.0f;
    }
  }
}

// ===========================================================================
// Mono cooperative kernel (grid 512, 2 blocks/CU guaranteed by bounds)
// ===========================================================================
struct P1Lds { float4 qb[QT]; float4 qn[QT]; float tile[QT * 65]; };
struct P2Lds { u64 tmin[256]; u64 cmin[64]; u64 surv[512]; u64 sorted[TOPC]; u64 thr; int ns; };

__global__ __launch_bounds__(256, 2) void mono_kernel(
    const float* __restrict__ logits, const float* __restrict__ boxes,
    const int* __restrict__ gtc, const float* __restrict__ gtb,
    const float* __restrict__ szout, const float* __restrict__ sztgt,
    float* __restrict__ cost, int* __restrict__ rowarg,
    short* __restrict__ lists, int* __restrict__ dynks,
    float* __restrict__ out_match, float* __restrict__ out_ids) {
  __shared__ __align__(16) union { P1Lds p1; P2Lds p2; SerialLds p3; } smem;
  const int tid = threadIdx.x;

  // phase 1: cost tiles
  for (int job = blockIdx.x; job < 63 * BB; job += gridDim.x) {
    cost_job(job / 63, (job % 63) * QT, tid, logits, boxes, gtc, gtb, szout,
             sztgt, cost, rowarg, out_match, smem.p1.qb, smem.p1.qn, smem.p1.tile);
  }
  __threadfence();
  cg::this_grid().sync();

  // phase 2: pick
  for (int bc = blockIdx.x; bc < BB * GG; bc += gridDim.x) {
    pick_job(bc, tid, boxes, gtb, cost, lists, dynks, smem.p2.tmin,
             smem.p2.cmin, smem.p2.surv, smem.p2.sorted, &smem.p2.thr, &smem.p2.ns);
  }
  __threadfence();
  cg::this_grid().sync();

  // phase 3: serial (blocks 0..31)
  if (blockIdx.x < BB)
    serial_job(blockIdx.x, tid, &smem.p3, cost, lists, dynks, rowarg,
               out_match, out_ids);
}

// ===========================================================================
// Fallback 3-kernel path (identical semantics, proven R10)
// ===========================================================================
__global__ __launch_bounds__(256) void cost_kernel(
    const float* __restrict__ logits, const float* __restrict__ boxes,
    const int* __restrict__ gtc, const float* __restrict__ gtb,
    const float* __restrict__ szout, const float* __restrict__ sztgt,
    float* __restrict__ cost, int* __restrict__ rowarg,
    float* __restrict__ out_match) {
  __shared__ __align__(16) P1Lds s;
  cost_job(blockIdx.y, blockIdx.x * QT, threadIdx.x, logits, boxes, gtc, gtb,
           szout, sztgt, cost, rowarg, out_match, s.qb, s.qn, s.tile);
}

__global__ __launch_bounds__(256) void pick_kernel(
    const float* __restrict__ boxes, const float* __restrict__ gtb,
    const float* __restrict__ cost, short* __restrict__ lists,
    int* __restrict__ dynks) {
  __shared__ __align__(16) P2Lds s;
  pick_job(blockIdx.x, threadIdx.x, boxes, gtb, cost, lists, dynks,
           s.tmin, s.cmin, s.surv, s.sorted, &s.thr, &s.ns);
}

__global__ __launch_bounds__(256) void serial_kernel(
    const float* __restrict__ cost, const short* __restrict__ lists,
    const int* __restrict__ dynks, const int* __restrict__ rowarg,
    float* __restrict__ out_match, float* __restrict__ out_ids) {
  __shared__ __align__(16) SerialLds s;
  serial_job(blockIdx.x, threadIdx.x, &s, cost, lists, dynks, rowarg,
             out_match, out_ids);
}

extern "C" void kernel_launch(void* const* d_in, const int* in_sizes, int n_in,
                              void* d_out, int out_size, void* d_ws, size_t ws_size,
                              hipStream_t stream) {
  const float* logits = (const float*)d_in[0];
  const float* boxes  = (const float*)d_in[1];
  const int*   gtc    = (const int*)d_in[2];
  const float* gtbx   = (const float*)d_in[3];
  const float* szout  = (const float*)d_in[4];
  const float* sztgt  = (const float*)d_in[5];
  float* out = (float*)d_out;

  const size_t matchN  = (size_t)BB * QQ * GG;
  const size_t rowargN = (size_t)BB * QQ;
  const size_t listsN  = (size_t)BB * GG * TOPC;

  char* p = (char*)d_ws;
  float* cost   = (float*)p;          p += matchN * 4;
  int*   rowarg = (int*)p;            p += rowargN * 4;
  short* lists  = (short*)p;          p += listsN * 2;
  int*   dynks  = (int*)p;

  float* out_ids = out + matchN;

  // try mono cooperative launch, verified against occupancy; else fallback
  int nb = 0;
  hipError_t oe = hipOccupancyMaxActiveBlocksPerMultiprocessor(
      &nb, (const void*)mono_kernel, 256, 0);
  bool ok = (oe == hipSuccess) && (nb >= 1);
  if (ok) {
    int grid = 256 * nb;
    if (grid > 512) grid = 512;
    if (grid < BB) ok = false;
    if (ok) {
      void* args[] = {
        (void*)&logits, (void*)&boxes, (void*)&gtc, (void*)&gtbx,
        (void*)&szout, (void*)&sztgt, (void*)&cost, (void*)&rowarg,
        (void*)&lists, (void*)&dynks, (void*)&out, (void*)&out_ids,
      };
      hipError_t le = hipLaunchCooperativeKernel(
          (const void*)mono_kernel, dim3(grid), dim3(256), args, 0, stream);
      if (le != hipSuccess) ok = false;
    }
  }
  if (!ok) {
    hipLaunchKernelGGL(cost_kernel, dim3((QQ + QT - 1) / QT, BB), dim3(256), 0,
                       stream, logits, boxes, gtc, gtbx, szout, sztgt, cost,
                       rowarg, out);
    hipLaunchKernelGGL(pick_kernel, dim3(BB * GG), dim3(256), 0, stream,
                       boxes, gtbx, cost, lists, dynks);
    hipLaunchKernelGGL(serial_kernel, dim3(BB), dim3(256), 0, stream,
                       cost, lists, dynks, rowarg, out, out_ids);
  }
}

// Round 12
// 125.878 us; speedup vs baseline: 2.6470x; 2.6470x over previous
//
#include <hip/hip_runtime.h>
#include <cmath>

#pragma clang fp contract(off)

#define BB 32
#define QQ 2000
#define GG 64
#define CCH 80
#define TOPC 16
#define QT 32

typedef unsigned long long u64;

// ---------------------------------------------------------------------------
// K1: cost matrix in [b][g][q] layout + per-query row argmin + zero-fill of
// the matching output region. (proven R8/R10)
// ---------------------------------------------------------------------------
__global__ __launch_bounds__(256) void cost_kernel(
    const float* __restrict__ logits, const float* __restrict__ boxes,
    const int* __restrict__ gtc, const float* __restrict__ gtb,
    const float* __restrict__ szout, const float* __restrict__ sztgt,
    float* __restrict__ cost, int* __restrict__ rowarg,
    float* __restrict__ out_match) {
#pragma clang fp contract(off)
  const int b = blockIdx.y;
  const int q0 = blockIdx.x * QT;
  const int t = threadIdx.x;
  const int w = t >> 6, lane = t & 63;

  __shared__ float4 s_qb[QT];
  __shared__ float4 s_qn[QT];
  __shared__ float s_tile[QT * 65];

  const int gbase = (b * GG + lane) * 4;
  const float g0 = gtb[gbase + 0], g1 = gtb[gbase + 1];
  const float g2 = gtb[gbase + 2], g3 = gtb[gbase + 3];
  const float t0 = g0 / sztgt[gbase + 0], t1 = g1 / sztgt[gbase + 1];
  const float t2 = g2 / sztgt[gbase + 2], t3 = g3 / sztgt[gbase + 3];
  const float garea = (g2 - g0) * (g3 - g1);
  const float gcx = (g0 + g2) * 0.5f, gcy = (g1 + g3) * 0.5f;
  const float gw = g2 - g0, gh = g3 - g1;
  const float cxlo = gcx - 2.5f * gw, cxhi = gcx + 2.5f * gw;
  const float cylo = gcy - 2.5f * gh, cyhi = gcy + 2.5f * gh;
  const int cls = gtc[b * GG + lane];

  if (t < QT) {
    int q = q0 + t;
    float4 bx = (q < QQ) ? reinterpret_cast<const float4*>(boxes)[b * QQ + q]
                         : make_float4(0.f, 0.f, 1.f, 1.f);
    s_qb[t] = bx;
    float4 on;
    on.x = bx.x / szout[b * 4 + 0];
    on.y = bx.y / szout[b * 4 + 1];
    on.z = bx.z / szout[b * 4 + 2];
    on.w = bx.w / szout[b * 4 + 3];
    s_qn[t] = on;
  }

  const float* lbase = logits + (size_t)b * QQ * CCH;
  float pv[8];
  #pragma unroll
  for (int i = 0; i < 8; ++i) {
    int q = q0 + w * 8 + i;
    pv[i] = (q < QQ) ? lbase[(size_t)q * CCH + cls] : 0.5f;
  }
  __syncthreads();

  #pragma unroll
  for (int i = 0; i < 8; ++i) {
    const int qi = w * 8 + i;
    float4 bx = s_qb[qi];
    float4 on = s_qn[qi];
    float x1 = bx.x, y1 = bx.y, x2 = bx.z, y2 = bx.w;
    float cx = (x1 + x2) * 0.5f, cy = (y1 + y2) * 0.5f;
    float areaa = (x2 - x1) * (y2 - y1);

    bool ib = (cx > g0) & (cx < g2) & (cy > g1) & (cy < g3);
    bool ic = (cx > cxlo) & (cx < cxhi) & (cy > cylo) & (cy < cyhi);
    bool fg = (__ballot(ib) != 0ull) || (__ballot(ic) != 0ull);
    float fgadd = fg ? 0.0f : 1e4f;

    float ltx = fmaxf(x1, g0), lty = fmaxf(y1, g1);
    float rbx = fminf(x2, g2), rby = fminf(y2, g3);
    float iw = fmaxf(rbx - ltx, 0.0f), ih = fmaxf(rby - lty, 0.0f);
    float inter = iw * ih;
    float uni = (areaa + garea) - inter;
    float iou = inter / uni;
    float ex1 = fminf(x1, g0), ey1 = fminf(y1, g1);
    float ex2 = fmaxf(x2, g2), ey2 = fmaxf(y2, g3);
    float ew = fmaxf(ex2 - ex1, 0.0f), eh = fmaxf(ey2 - ey1, 0.0f);
    float areac = ew * eh;
    float giou = iou - (areac - uni) / areac;

    float p = pv[i];
    float negc = (0.75f * (p * p)) * (-logf((1.0f - p) + 1e-8f));
    float posc = (0.25f * ((1.0f - p) * (1.0f - p))) * (-logf(p + 1e-8f));
    float ccls = posc - negc;

    float cb = ((fabsf(on.x - t0) + fabsf(on.y - t1)) + fabsf(on.z - t2)) + fabsf(on.w - t3);
    float notbc = (ib & ic) ? 0.0f : 1.0f;
    float c = ((5.0f * cb + 2.0f * ccls) + 2.0f * (-giou)) + 100.0f * notbc;
    c = c + fgadd;

    s_tile[qi * 65 + lane] = c;
  }
  __syncthreads();

  if (t < QT) {
    int q = q0 + t;
    if (q < QQ) {
      const float* row = &s_tile[t * 65];
      float bv = row[0]; int bg = 0;
      #pragma unroll
      for (int g = 1; g < GG; ++g) {
        float cv = row[g];
        if (cv < bv) { bv = cv; bg = g; }
      }
      rowarg[b * QQ + q] = bg;
    }
  }

  float* cb_out = cost + (size_t)b * GG * QQ;
  const int qi = t & 31;
  const int q = q0 + qi;
  if (q < QQ) {
    #pragma unroll
    for (int pass = 0; pass < 8; ++pass) {
      int g = (t >> 5) + pass * 8;
      cb_out[(size_t)g * QQ + q] = s_tile[qi * 65 + g];
    }
  }

  int nq = QQ - q0; if (nq > QT) nq = QT;
  if (nq > 0) {
    float4* zb = reinterpret_cast<float4*>(out_match + ((size_t)b * QQ + q0) * GG);
    int n4 = nq * GG / 4;
    float4 z = make_float4(0.f, 0.f, 0.f, 0.f);
    for (int i = t; i < n4; i += 256) zb[i] = z;
  }
}

// ---------------------------------------------------------------------------
// block_select<TOPN>: exact sorted smallest-TOPN via threshold-filter + rank
// (proven R7/R8/R10)
// ---------------------------------------------------------------------------
template <int TOPN>
__device__ __forceinline__ void block_select(
    u64 (&K)[8], int tid, u64* s_tmin, u64* s_cmin, u64* s_surv,
    u64* s_sorted, u64* s_thr, int* s_ns) {
  u64 m = K[0];
  #pragma unroll
  for (int j = 1; j < 8; ++j) m = (K[j] < m) ? K[j] : m;
  s_tmin[tid] = m;
  if (tid == 0) *s_ns = 0;
  __syncthreads();

  if (tid < 64) {
    u64 c = s_tmin[tid];
    u64 c1 = s_tmin[tid + 64], c2 = s_tmin[tid + 128], c3 = s_tmin[tid + 192];
    c = (c1 < c) ? c1 : c; c = (c2 < c) ? c2 : c; c = (c3 < c) ? c3 : c;
    s_cmin[tid] = c;
    int r = 0;
    for (int j = 0; j < 64; ++j) r += (s_cmin[j] < c) ? 1 : 0;
    if (r == TOPN - 1) *s_thr = c;
  }
  __syncthreads();

  const u64 t = *s_thr;
  int n = 0;
  #pragma unroll
  for (int j = 0; j < 8; ++j) n += (K[j] <= t) ? 1 : 0;
  if (n) {
    int base = atomicAdd(s_ns, n);
    int k = 0;
    #pragma unroll
    for (int j = 0; j < 8; ++j) if (K[j] <= t) s_surv[base + (k++)] = K[j];
  }
  __syncthreads();

  const int ns = *s_ns;
  if (ns <= 64) {
    if (tid < ns && tid < 64) {
      u64 k = s_surv[tid];
      int r = 0;
      for (int j = 0; j < ns; ++j) r += (s_surv[j] < k) ? 1 : 0;
      if (r < TOPN) s_sorted[r] = k;
    }
  } else if (tid < 64) {
    for (int pass = 0; pass < TOPN; ++pass) {
      u64 bk = ~0ull;
      for (int idx = tid; idx < ns; idx += 64) {
        u64 v = s_surv[idx]; bk = (v < bk) ? v : bk;
      }
      for (int off = 32; off; off >>= 1) {
        u64 ok = __shfl_down(bk, off, 64); bk = (ok < bk) ? ok : bk;
      }
      bk = __shfl(bk, 0, 64);
      for (int idx = tid; idx < ns; idx += 64)
        if (s_surv[idx] == bk) s_surv[idx] = ~0ull;
      if (tid == 0) s_sorted[pass] = bk;
    }
  }
  __syncthreads();
}

// ---------------------------------------------------------------------------
// K2a: pick (proven R8/R10)
// ---------------------------------------------------------------------------
__global__ __launch_bounds__(256) void pick_kernel(
    const float* __restrict__ boxes, const float* __restrict__ gtb,
    const float* __restrict__ cost, short* __restrict__ lists,
    int* __restrict__ dynks) {
#pragma clang fp contract(off)
  const int bc = blockIdx.x;
  const int b = bc >> 6, col = bc & 63;
  const int tid = threadIdx.x;

  __shared__ u64 s_tmin[256];
  __shared__ u64 s_cmin[64];
  __shared__ u64 s_surv[512];
  __shared__ u64 s_sorted[TOPC];
  __shared__ u64 s_thr;
  __shared__ int s_ns;

  const int gbase = (b * GG + col) * 4;
  const float gx1 = gtb[gbase + 0], gy1 = gtb[gbase + 1];
  const float gx2 = gtb[gbase + 2], gy2 = gtb[gbase + 3];
  const float ga = (gx2 - gx1) * (gy2 - gy1);

  u64 K[8];
  #pragma unroll
  for (int j = 0; j < 8; ++j) {
    int q = tid * 8 + j;
    float val = -1e30f;
    if (q < QQ) {
      float4 bx = reinterpret_cast<const float4*>(boxes)[b * QQ + q];
      float areaa = (bx.z - bx.x) * (bx.w - bx.y);
      float ltx = fmaxf(bx.x, gx1), lty = fmaxf(bx.y, gy1);
      float rbx = fminf(bx.z, gx2), rby = fminf(bx.w, gy2);
      float iw = fmaxf(rbx - ltx, 0.0f), ih = fmaxf(rby - lty, 0.0f);
      float inter = iw * ih;
      val = inter / ((areaa + ga) - inter);
    }
    unsigned u = __float_as_uint(val);
    u = (u & 0x80000000u) ? ~u : (u | 0x80000000u);
    K[j] = ~(((u64)u << 16) | (u64)(0xFFFF - q));
  }
  block_select<5>(K, tid, s_tmin, s_cmin, s_surv, s_sorted, &s_thr, &s_ns);
  if (tid == 0) {
    float s = 0.0f;
    for (int r = 0; r < 5; ++r) {
      u64 kk = ~s_sorted[r];
      unsigned u = (unsigned)(kk >> 16);
      u = (u & 0x80000000u) ? (u & 0x7FFFFFFFu) : ~u;
      s += __uint_as_float(u);
    }
    int dynk = (int)s;
    if (dynk < 1) dynk = 1;
    dynks[bc] = dynk;
  }

  const float* ccol = cost + (size_t)bc * QQ;
  {
    float cv[8];
    if (tid < 249) {
      const float4* c4 = reinterpret_cast<const float4*>(ccol) + tid * 2;
      float4 a = c4[0], d = c4[1];
      cv[0] = a.x; cv[1] = a.y; cv[2] = a.z; cv[3] = a.w;
      cv[4] = d.x; cv[5] = d.y; cv[6] = d.z; cv[7] = d.w;
    } else {
      #pragma unroll
      for (int j = 0; j < 8; ++j) {
        int q = tid * 8 + j;
        cv[j] = (q < QQ) ? ccol[q] : INFINITY;
      }
    }
    #pragma unroll
    for (int j = 0; j < 8; ++j) {
      unsigned u = __float_as_uint(cv[j]);
      u = (u & 0x80000000u) ? ~u : (u | 0x80000000u);
      K[j] = ((u64)u << 16) | (u64)(tid * 8 + j);
    }
  }
  block_select<TOPC>(K, tid, s_tmin, s_cmin, s_surv, s_sorted, &s_thr, &s_ns);
  if (tid < TOPC) lists[bc * TOPC + tid] = (short)(s_sorted[tid] & 0xFFFFull);
}

// ---------------------------------------------------------------------------
// K2b: serial per-batch loop (proven R10: candidates in registers, monotone
// byte matched-flag, zero-barrier single-wave loop)
// ---------------------------------------------------------------------------
__global__ __launch_bounds__(256) void serial_kernel(
    const float* __restrict__ cost, const short* __restrict__ lists,
    const int* __restrict__ dynks, const int* __restrict__ rowarg,
    float* __restrict__ out_match, float* __restrict__ out_ids) {
#pragma clang fp contract(off)
  const int b = blockIdx.x;
  const int tid = threadIdx.x;

  __shared__ unsigned s_mlo[QQ], s_mhi[QQ];
  __shared__ int s_first[QQ];
  __shared__ unsigned char s_mq[QQ];
  __shared__ short s_rarg[QQ];
  __shared__ int s_cnt[GG];
  __shared__ u64 s_pack[GG];
  __shared__ int s_added[GG];
  __shared__ int s_nadd, s_Tv;

  for (int q = tid; q < QQ; q += 256) {
    s_mlo[q] = 0u; s_mhi[q] = 0u; s_first[q] = -1; s_mq[q] = 0;
    s_rarg[q] = (short)rowarg[b * QQ + q];
  }
  if (tid < GG) s_cnt[tid] = 0;
  __syncthreads();

  if (tid < GG) {
    int dynk = dynks[b * GG + tid];
    s_cnt[tid] = dynk;
    const short* lrow = lists + (b * GG + tid) * TOPC;
    for (int i = 0; i < dynk; ++i) {
      int q = lrow[i];
      if (tid < 32) atomicOr(&s_mlo[q], 1u << tid);
      else          atomicOr(&s_mhi[q], 1u << (tid - 32));
      s_first[q] = 0;
      s_mq[q] = 1;
    }
  }
  __syncthreads();

  for (int q = tid; q < QQ; q += 256) {
    unsigned lo = s_mlo[q], hi = s_mhi[q];
    if (__popc(lo) + __popc(hi) > 1) {
      int bg = s_rarg[q];
      unsigned tl = lo, th = hi;
      while (tl) { int g = __ffs(tl) - 1; tl &= tl - 1; if (g != bg) atomicSub(&s_cnt[g], 1); }
      while (th) { int g = __ffs(th) + 31; th &= th - 1; if (g != bg) atomicSub(&s_cnt[g], 1); }
      bool had = (bg < 32) ? ((lo >> bg) & 1u) : ((hi >> (bg - 32)) & 1u);
      if (!had) atomicAdd(&s_cnt[bg], 1);
      s_mlo[q] = (bg < 32) ? (1u << bg) : 0u;
      s_mhi[q] = (bg >= 32) ? (1u << (bg - 32)) : 0u;
    }
  }
  __syncthreads();

  const float* costb = cost + (size_t)b * GG * QQ;

  if (tid < 64) {
    const int lane = tid;
    unsigned cand[8];
    {
      const unsigned* lrow =
          reinterpret_cast<const unsigned*>(lists + (b * GG + lane) * TOPC);
      #pragma unroll
      for (int j = 0; j < 8; ++j) cand[j] = lrow[j];
    }
    int T = 0;
    for (int iter = 0; iter < GG; ++iter) {
      unsigned long long bal = __ballot(s_cnt[lane] > 0);
      unsigned long long um = ~bal;
      if (um == 0ull) break;
      T++;
      bool isun = (um >> lane) & 1ull;
      if (lane == 0) s_nadd = 0;

      int myq = -1;
      unsigned fmask = 0;
      if (isun) {
        #pragma unroll
        for (int i = 0; i < 16; ++i) {
          int cq = (cand[i >> 1] >> (16 * (i & 1))) & 0xFFFF;
          fmask |= ((unsigned)(s_mq[cq] == 0)) << i;
        }
        if (fmask) {
          int idx = __ffs(fmask) - 1;
          myq = (cand[idx >> 1] >> (16 * (idx & 1))) & 0xFFFF;
        }
      }

      unsigned long long fb = __ballot(isun && fmask == 0);
      while (fb) {
        int col = __ffsll(fb) - 1; fb &= fb - 1;
        const float* ccol = costb + (size_t)col * QQ;
        float bv = INFINITY; int bq = 0x7fffffff;
        for (int q2 = lane; q2 < QQ; q2 += 64) {
          if (s_mq[q2] == 0) {
            float cv = ccol[q2];
            if (cv < bv) { bv = cv; bq = q2; }
          }
        }
        for (int off = 32; off; off >>= 1) {
          float ov = __shfl_down(bv, off, 64); int oq = __shfl_down(bq, off, 64);
          if (ov < bv || (ov == bv && oq < bq)) { bv = ov; bq = oq; }
        }
        bq = __shfl(bq, 0, 64);
        if (bq == 0x7fffffff) {
          bv = INFINITY; bq = 0x7fffffff;
          for (int q2 = lane; q2 < QQ; q2 += 64) {
            float cv = ccol[q2];
            int k = (s_first[q2] >= 0) ? (iter + 1 - s_first[q2]) : 0;
            for (int tt = 0; tt < k; ++tt) cv += 1e5f;
            if (cv < bv) { bv = cv; bq = q2; }
          }
          for (int off = 32; off; off >>= 1) {
            float ov = __shfl_down(bv, off, 64); int oq = __shfl_down(bq, off, 64);
            if (ov < bv || (ov == bv && oq < bq)) { bv = ov; bq = oq; }
          }
          bq = __shfl(bq, 0, 64);
        }
        if (lane == col) myq = bq;
      }

      if (isun) {
        int q = myq;
        if (lane < 32) atomicOr(&s_mlo[q], 1u << lane);
        else           atomicOr(&s_mhi[q], 1u << (lane - 32));
        atomicAdd(&s_cnt[lane], 1);
        if (s_first[q] < 0) s_first[q] = iter + 1;
        s_mq[q] = 1;
        int slot = atomicAdd(&s_nadd, 1);
        s_added[slot] = q;
      }

      int na = s_nadd;
      if (lane < na) {
        int q = s_added[lane];
        bool dup = false;
        for (int j = 0; j < lane; ++j) dup = dup || (s_added[j] == q);
        if (!dup) {
          unsigned lo = s_mlo[q], hi = s_mhi[q];
          if (__popc(lo) + __popc(hi) > 1) {
            int bg = s_rarg[q];
            unsigned tl = lo, th = hi;
            while (tl) { int g = __ffs(tl) - 1; tl &= tl - 1; if (g != bg) atomicSub(&s_cnt[g], 1); }
            while (th) { int g = __ffs(th) + 31; th &= th - 1; if (g != bg) atomicSub(&s_cnt[g], 1); }
            bool had = (bg < 32) ? ((lo >> bg) & 1u) : ((hi >> (bg - 32)) & 1u);
            if (!had) atomicAdd(&s_cnt[bg], 1);
            s_mlo[q] = (bg < 32) ? (1u << bg) : 0u;
            s_mhi[q] = (bg >= 32) ? (1u << (bg - 32)) : 0u;
          }
        }
      }
    }
    if (tid == 0) s_Tv = T;
  }
  __syncthreads();
  const int T = s_Tv;

  if (tid < GG) s_pack[tid] = 0xFFFFFFFFFFFFFFFFull;
  __syncthreads();
  for (int q = tid; q < QQ; q += 256) {
    unsigned lo = s_mlo[q], hi = s_mhi[q];
    if (lo | hi) {
      int g = lo ? (__ffs(lo) - 1) : (__ffs(hi) + 31);
      float cv = costb[(size_t)g * QQ + q];
      int k = T - s_first[q];
      for (int tt = 0; tt < k; ++tt) cv += 1e5f;
      unsigned ub = __float_as_uint(cv);
      ub = (ub & 0x80000000u) ? ~ub : (ub | 0x80000000u);
      u64 pk = ((u64)ub << 16) | (unsigned)q;
      atomicMin(&s_pack[g], pk);
    }
  }
  __syncthreads();
  if (tid < GG) {
    u64 pk = s_pack[tid];
    out_ids[b * GG + tid] =
        (pk == 0xFFFFFFFFFFFFFFFFull) ? 0.0f : (float)(pk & 0xFFFFull);
  }
  for (int q = tid; q < QQ; q += 256) {
    unsigned lo = s_mlo[q], hi = s_mhi[q];
    if (lo | hi) {
      int g = lo ? (__ffs(lo) - 1) : (__ffs(hi) + 31);
      out_match[((size_t)b * QQ + q) * GG + g] = 1.0f;
    }
  }
}

extern "C" void kernel_launch(void* const* d_in, const int* in_sizes, int n_in,
                              void* d_out, int out_size, void* d_ws, size_t ws_size,
                              hipStream_t stream) {
  const float* logits = (const float*)d_in[0];
  const float* boxes  = (const float*)d_in[1];
  const int*   gtc    = (const int*)d_in[2];
  const float* gtbx   = (const float*)d_in[3];
  const float* szout  = (const float*)d_in[4];
  const float* sztgt  = (const float*)d_in[5];
  float* out = (float*)d_out;

  const size_t matchN  = (size_t)BB * QQ * GG;
  const size_t rowargN = (size_t)BB * QQ;
  const size_t listsN  = (size_t)BB * GG * TOPC;

  char* p = (char*)d_ws;
  float* cost   = (float*)p;          p += matchN * 4;
  int*   rowarg = (int*)p;            p += rowargN * 4;
  short* lists  = (short*)p;          p += listsN * 2;
  int*   dynks  = (int*)p;

  float* out_ids = out + matchN;

  hipLaunchKernelGGL(cost_kernel, dim3((QQ + QT - 1) / QT, BB), dim3(256), 0, stream,
                     logits, boxes, gtc, gtbx, szout, sztgt, cost, rowarg, out);
  hipLaunchKernelGGL(pick_kernel, dim3(BB * GG), dim3(256), 0, stream,
                     boxes, gtbx, cost, lists, dynks);
  hipLaunchKernelGGL(serial_kernel, dim3(BB), dim3(256), 0, stream,
                     cost, lists, dynks, rowarg, out, out_ids);
}